// Round 5
// baseline (205.825 us; speedup 1.0000x reference)
//
#include <hip/hip_runtime.h>
#include <hip/hip_bf16.h>

// Problem: B=256, T=256, C=384, H=64, MAX_REL=3 (causal -> rel idx 0..3 only)
// Round 12: consolidation. r8-r11: four structurally different schedules all
// land at 76-79 us (MfmaUtil ~6, VALU ~13, HBM ~16%) -> the fused kernel is
// pinned by something the schedule tweaks don't reach. What IS bankable:
// end-to-end = fill(59, harness) + prep(2) + fused(78) + ~50 us launch gaps.
// This round removes a whole dispatch: prep_wt folded into the fused kernel
// (per-block W f32->bf16^T conversion into LDS, coalesced + L3-hot, hidden
// under the x chunk-0 HBM latency; Rk built in LDS too). Plus s_setprio(1)
// around MFMA clusters (T5: phase-2 has wave role diversity).
//   - ONE kernel, zero workspace. Grid 256 x 1024 thr, 153856 B dynamic LDS.
//   - phase 1/2 structure = r11 verbatim otherwise.

typedef __attribute__((ext_vector_type(8))) __bf16 bf16x8;
typedef __attribute__((ext_vector_type(8))) short short8;
typedef __attribute__((ext_vector_type(4))) float f32x4;
typedef __attribute__((ext_vector_type(4))) int   i32x4;

#define MFMA16(A, B, C) __builtin_amdgcn_mfma_f32_16x16x32_bf16((A), (B), (C), 0, 0, 0)

__device__ __forceinline__ unsigned short f2bf(float f) {
    unsigned int u = __builtin_bit_cast(unsigned int, f);
    u = (u + 0x7FFFu + ((u >> 16) & 1u)) >> 16;   // RNE
    return (unsigned short)u;
}
__device__ __forceinline__ float bf2f(unsigned short s) {
    unsigned int u = ((unsigned int)s) << 16;
    return __builtin_bit_cast(float, u);
}
__device__ __forceinline__ bf16x8 ld16(const unsigned short* p) {
    return __builtin_bit_cast(bf16x8, *(const i32x4*)p);
}

// ---------------------------------------------------------------------------
// Fused prep + QKV + attention. One block per batch, 1024 threads (16 waves).
// LDS (u16 offsets; dynamic request 153856 B = 76928 u16):
//   phase 1: ws [192][392] @ 0          150528 B  (whole W^T, staged once)
//   phase 2 overlays ws:
//     ksh [256][72] @ 0; vTs [64][264] @ 18432; qs [256][72] @ 35328
//     P(pair p) = 35328 + p*4224, [16][264]  (ends 69120)
//   outside overlay (persistent):
//     lsum f32[256] @ u16 75264 ; Rkl [16][72] @ u16 75776 (ends 76928)
// ---------------------------------------------------------------------------
__global__ __launch_bounds__(1024)
__attribute__((amdgpu_waves_per_eu(4, 4)))
void fused_kernel(
        const float* __restrict__ x,
        const float* __restrict__ Wq, const float* __restrict__ Wk,
        const float* __restrict__ Wv, const float* __restrict__ relk,
        const float* __restrict__ relv, float* __restrict__ out) {
    extern __shared__ unsigned short sh[];
    unsigned short* ws  = sh;                  // phase 1
    unsigned short* ksh = sh;                  // phase 2
    unsigned short* vTs = sh + 18432;
    unsigned short* qs  = sh + 35328;
    float* lsum = (float*)(sh + 75264);
    unsigned short* Rkl = sh + 75776;          // [16][72]

    const int tid  = threadIdx.x;
    const int wave = tid >> 6;
    const int lane = tid & 63;
    const int c    = lane & 15;
    const int quad = lane >> 4;
    const int b    = blockIdx.x;

    const f32x4 zero = {0.f, 0.f, 0.f, 0.f};

    // =================== prologue: x prefetch + W/Rk staging =================
    // wave owns rows wave*16 + c ; lane reads its row at cols quad*8..+7 per j
    const float* xbase = x + (size_t)(b * 256 + wave * 16 + c) * 384 + quad * 8;

    f32x4 aq[4], ak[4], av[4];
#pragma unroll
    for (int nt = 0; nt < 4; nt++) { aq[nt] = zero; ak[nt] = zero; av[nt] = zero; }

    // issue x chunk-0 loads FIRST (HBM long pole); staging hides under them
    f32x4 tmp[8];
#pragma unroll
    for (int j = 0; j < 4; j++) {
        tmp[2 * j]     = *(const f32x4*)(xbase + j * 32);
        tmp[2 * j + 1] = *(const f32x4*)(xbase + j * 32 + 4);
    }

    // Rk rows 0..3 valid, 4..15 zero (one entry per thread), stride 72
    {
        int n = tid >> 6, h = tid & 63;
        Rkl[n * 72 + h] = (n < 4) ? f2bf(relk[n * 64 + h]) : (unsigned short)0;
    }

    // W^T staging straight from f32 sources (L3-hot): 18432 f32x4 pieces,
    // 18/thread; coalesced 16B global reads, scalar u16 transposed LDS writes.
#pragma unroll
    for (int it = 0; it < 18; it++) {
        int P_  = it * 1024 + tid;
        int w   = P_ / 6144;                   // 0..2 : Wq / Wk / Wv
        int rem = P_ - w * 6144;
        int k   = rem >> 4;
        int h4  = (rem & 15) * 4;
        const float* Wp = (w == 0) ? Wq : ((w == 1) ? Wk : Wv);
        f32x4 d = *(const f32x4*)(Wp + k * 64 + h4);
#pragma unroll
        for (int e = 0; e < 4; e++)
            ws[(w * 64 + h4 + e) * 392 + k] = f2bf(d[e]);
    }
    __syncthreads();                           // W^T + Rk resident

    // =================== phase 1: QKV GEMM (barrier-free main loop) =========
#pragma unroll
    for (int ck = 0; ck < 3; ck++) {
        // convert this chunk's x to bf16 A-frags (frees tmp for the prefetch)
        bf16x8 a[4];
#pragma unroll
        for (int j = 0; j < 4; j++) {
            short8 xs8;
#pragma unroll
            for (int e = 0; e < 4; e++) {
                xs8[e]     = (short)f2bf(tmp[2 * j][e]);
                xs8[4 + e] = (short)f2bf(tmp[2 * j + 1][e]);
            }
            a[j] = __builtin_bit_cast(bf16x8, xs8);
        }
        // prefetch next chunk's x; lands during the MFMA loop below
        if (ck < 2) {
#pragma unroll
            for (int j = 0; j < 4; j++) {
                const float* xp = xbase + (ck + 1) * 128 + j * 32;
                tmp[2 * j]     = *(const f32x4*)xp;
                tmp[2 * j + 1] = *(const f32x4*)(xp + 4);
            }
        }

        __builtin_amdgcn_s_setprio(1);
#pragma unroll
        for (int j = 0; j < 4; j++) {
            const int col = ck * 128 + j * 32 + quad * 8;
#pragma unroll
            for (int nt = 0; nt < 4; nt++) {
                bf16x8 bq = ld16(ws + (nt * 16 + c) * 392 + col);
                bf16x8 bk = ld16(ws + (64 + nt * 16 + c) * 392 + col);
                bf16x8 aw = ld16(ws + (128 + nt * 16 + c) * 392 + col);
                aq[nt] = MFMA16(a[j], bq, aq[nt]);   // D[t][h]
                ak[nt] = MFMA16(a[j], bk, ak[nt]);   // D[t][h]
                av[nt] = MFMA16(aw, a[j], av[nt]);   // D[h][t]
            }
        }
        __builtin_amdgcn_s_setprio(0);
    }
    __syncthreads();                           // all W reads done -> may overwrite

    // epilogue into LDS (C/D layout: col=lane&15, row=quad*4+reg)
#pragma unroll
    for (int nt = 0; nt < 4; nt++)
#pragma unroll
        for (int r = 0; r < 4; r++) {
            int row = wave * 16 + quad * 4 + r;
            qs[row * 72 + nt * 16 + c]  = f2bf(aq[nt][r]);
            ksh[row * 72 + nt * 16 + c] = f2bf(ak[nt][r]);
            vTs[(nt * 16 + quad * 4 + r) * 264 + wave * 16 + c] = f2bf(av[nt][r]);
        }
    __syncthreads();                           // q/k/vT visible to all waves

    // =================== phase 2: attention from LDS ===================
    // pair p = wave&7 handles q-tiles {p, 15-p}; hi = wave>>3 is the pair half.
    // scores split by s-tile parity; PV + output split by nt (2 per wave).
    const int p  = wave & 7;
    const int hi = wave >> 3;
    const int tA = p, tB = 15 - p;

    bf16x8 qA0 = ld16(qs + (tA * 16 + c) * 72 + quad * 8);
    bf16x8 qA1 = ld16(qs + (tA * 16 + c) * 72 + 32 + quad * 8);
    bf16x8 qB0 = ld16(qs + (tB * 16 + c) * 72 + quad * 8);
    bf16x8 qB1 = ld16(qs + (tB * 16 + c) * 72 + 32 + quad * 8);
    float rv[4][2];
#pragma unroll
    for (int j = 0; j < 4; j++)
#pragma unroll
        for (int i = 0; i < 2; i++)
            rv[j][i] = relv[j * 64 + (hi * 2 + i) * 16 + c];
    __syncthreads();                           // qs reads done -> P may overwrite

    unsigned short* Pw = sh + 35328 + p * 4224;    // per-PAIR [16][264]

#pragma unroll
    for (int it2 = 0; it2 < 2; it2++) {
        const int tt  = it2 ? tB : tA;
        const bf16x8 aq0 = it2 ? qB0 : qA0;
        const bf16x8 aq1 = it2 ? qB1 : qA1;
        const int nst = tt + 1;

        // E via MFMA vs Rk: D[m=quad*4+r][n=c] = q_{t0+m} . relk_n  (n<4 valid)
        f32x4 e = zero;
        e = MFMA16(aq0, ld16(Rkl + c * 72 + quad * 8), e);
        e = MFMA16(aq1, ld16(Rkl + c * 72 + 32 + quad * 8), e);
        float ef[4][4];
#pragma unroll
        for (int r = 0; r < 4; r++)
#pragma unroll
            for (int n = 0; n < 4; n++)
                ef[r][n] = __shfl(e[r], (lane & 48) + n, 64);

        // score tiles of my parity -> exp -> P^ in LDS; partial row sums
        float l[4] = {0.f, 0.f, 0.f, 0.f};
#pragma unroll
        for (int st = 0; st < 16; st++) {
            if ((st & 1) == hi) {
                if (st < nst) {
                    const unsigned short* kp = ksh + (st * 16 + c) * 72 + quad * 8;
                    f32x4 s = zero;
                    s = MFMA16(aq0, ld16(kp), s);
                    s = MFMA16(aq1, ld16(kp + 32), s);
#pragma unroll
                    for (int r = 0; r < 4; r++) {
                        int tg = tt * 16 + quad * 4 + r;
                        int sg = st * 16 + c;
                        int d  = sg - tg;
                        float ee = (d <= -3) ? ef[r][0] : (d == -2) ? ef[r][1]
                                 : (d == -1) ? ef[r][2] : ef[r][3];
                        float pv = (d > 0) ? 0.f : __expf(0.125f * (s[r] + ee));
                        l[r] += pv;
                        Pw[(quad * 4 + r) * 264 + sg] = f2bf(pv);
                    }
                } else if (st == nst && (nst & 1)) {
                    // zero-pad the half-open MFMA k-tile (odd nst -> parity 1)
#pragma unroll
                    for (int r = 0; r < 4; r++)
                        Pw[(quad * 4 + r) * 264 + st * 16 + c] = 0;
                }
            }
        }
        // partial row-sum over the 16 c-lanes, then exchange across the pair
#pragma unroll
        for (int r = 0; r < 4; r++)
#pragma unroll
            for (int ofs = 1; ofs < 16; ofs <<= 1)
                l[r] += __shfl_xor(l[r], ofs, 64);
        if (c == 0) {
#pragma unroll
            for (int r = 0; r < 4; r++)
                lsum[(p * 2 + hi) * 16 + quad * 4 + r] = l[r];
        }
        __syncthreads();                       // lsum + partner's P^ visible
        float rl[4];
#pragma unroll
        for (int r = 0; r < 4; r++)
            rl[r] = 1.0f / (l[r] + lsum[(p * 2 + (1 - hi)) * 16 + quad * 4 + r]);

        // O = P^ @ V for my 2 nt columns; accumulator chains split by ks parity
        f32x4 o0[2], o1[2];
        o0[0] = zero; o0[1] = zero; o1[0] = zero; o1[1] = zero;
        const int ksteps = (nst + 1) >> 1;
        __builtin_amdgcn_s_setprio(1);
#pragma unroll
        for (int ks = 0; ks < 8; ks++) {
            if (ks < ksteps) {
                bf16x8 ap = ld16(Pw + c * 264 + ks * 32 + quad * 8);
#pragma unroll
                for (int i = 0; i < 2; i++) {
                    const int nt = hi * 2 + i;
                    bf16x8 bv = ld16(vTs + (nt * 16 + c) * 264 + ks * 32 + quad * 8);
                    if (ks & 1) o1[i] = MFMA16(ap, bv, o1[i]);
                    else        o0[i] = MFMA16(ap, bv, o0[i]);
                }
            }
        }
        __builtin_amdgcn_s_setprio(0);

        // epilogue: normalize + w2 band-probability identity + store my 2 nt
#pragma unroll
        for (int r = 0; r < 4; r++) {
            int tl = quad * 4 + r;
            int tg = tt * 16 + tl;
            float pa  = (tg >= 2) ? bf2f(Pw[tl * 264 + tg - 2]) * rl[r] : 0.f;
            float pb  = (tg >= 1) ? bf2f(Pw[tl * 264 + tg - 1]) * rl[r] : 0.f;
            float pcv = bf2f(Pw[tl * 264 + tg]) * rl[r];
#pragma unroll
            for (int i = 0; i < 2; i++) {
                const int nt = hi * 2 + i;
                float r0 = rv[0][i];
                float w2 = r0 + pa * (rv[1][i] - r0) + pb * (rv[2][i] - r0)
                              + pcv * (rv[3][i] - r0);
                out[(size_t)(b * 256 + tg) * 64 + nt * 16 + c]
                    = (o0[i][r] + o1[i][r]) * rl[r] + w2;
            }
        }
        __syncthreads();                       // P^/lsum reads done before reuse
    }
}

// ---------------------------------------------------------------------------
extern "C" void kernel_launch(void* const* d_in, const int* in_sizes, int n_in,
                              void* d_out, int out_size, void* d_ws, size_t ws_size,
                              hipStream_t stream) {
    const float* x    = (const float*)d_in[0];
    const float* Wq   = (const float*)d_in[1];
    const float* Wk   = (const float*)d_in[2];
    const float* Wv   = (const float*)d_in[3];
    const float* relk = (const float*)d_in[4];
    const float* relv = (const float*)d_in[5];
    float* out = (float*)d_out;
    (void)d_ws; (void)ws_size; (void)in_sizes; (void)n_in; (void)out_size;

    (void)hipFuncSetAttribute((const void*)fused_kernel,
                              hipFuncAttributeMaxDynamicSharedMemorySize, 153856);

    fused_kernel<<<256, 1024, 153856, stream>>>(x, Wq, Wk, Wv, relk, relv, out);
}